// Round 4
// baseline (606.247 us; speedup 1.0000x reference)
//
#include <hip/hip_runtime.h>

// TurboFlashAttention: causal B=2,H=16,S=2048,D=64 fp32 + 512MB zero placeholder.
// R9: rate-matched in-loop fill. R8 proved the fill's non-overlap is NOT a
// waitcnt/barrier issue: with 16 chunks front-loaded into every block's first
// 16 iterations, all 512 blocks demand ~15-20 TB/s of store BW in the first
// ~35us -> HBM write queues fill -> waves stall mid-fill_chunk -> fill
// effectively serializes (R6==R7==R8). Fix: fill allocation proportional to
// iteration count. Block s fills 2s+1 chunks (offset s^2 within its bh's
// 256-chunk region; sum_{s}(2s+1)=256=16MiB/bh), ONE chunk per iteration
// (j=0..2s, skipping only the last iteration). Complementary CU pairing
// (s+s'=15) then gives every CU a constant 1 chunk/slot = 2MiB/34slots
// ~= 3.4 TB/s chip-wide (54% of HBM) -> fill hides under the compute wall.
// Raw lgkmcnt-only barrier kept so stores ride across iterations.

typedef __bf16 bf16x8 __attribute__((ext_vector_type(8)));
typedef float f32x4 __attribute__((ext_vector_type(4)));

#define LOG2E 1.44269504088896340736f

__device__ __forceinline__ unsigned short f2bf(float f) {
  unsigned int u = __float_as_uint(f);
  u += 0x7fffu + ((u >> 16) & 1u);   // RNE
  return (unsigned short)(u >> 16);
}

// Cross-wave LDS sync WITHOUT the vmcnt(0) drain __syncthreads would emit.
__device__ __forceinline__ void block_sync_lds() {
  asm volatile("s_waitcnt lgkmcnt(0)" ::: "memory");
  __builtin_amdgcn_s_barrier();
}

constexpr int Sdim = 2048, Ddim = 64, BHn = 32;
constexpr int STiles = 16;                   // 128-row q-supertiles
constexpr int LDK = 72;                      // LDS leading-dim pad (shorts)
constexpr int OUT0 = BHn * Sdim * Ddim;      // output-region floats
constexpr int CHUNK_F4 = 4096;               // 64 KiB fill chunk, in f32x4
constexpr int CHUNKS_PER_BH = 256;           // 16 MiB per bh; 32 bh = 512 MiB

__device__ __forceinline__ int vswz_m(int d) { return ((d >> 2) ^ (d >> 5)) & 7; }

__global__ __launch_bounds__(256, 2)
void flash_causal_kernel(const float* __restrict__ Q, const float* __restrict__ K,
                         const float* __restrict__ V, float* __restrict__ out) {
  __shared__ unsigned short Klds[2][64 * LDK];      // K tile [kn][d]
  __shared__ unsigned short Vlds[2][64 * LDK];      // V^T tile [d][kn^swz]
  __shared__ unsigned short Plds[4][2][16 * LDK];   // per-wave, per-frag P^T

  const int tid  = threadIdx.x;
  const int wave = tid >> 6;
  const int lane = tid & 63;
  const int quad = lane >> 4;
  const int l15  = lane & 15;

  const int bh = blockIdx.x & (BHn - 1);
  const int g  = (int)(blockIdx.x >> 5);                  // 0..15
  // Complementary co-residency pairing: blocks (i, i+256) share a CU (XCD
  // round-robin); their g differ by 8. s(g)+s(g+8) == 15 -> per-CU iteration
  // count (34) and per-CU fill rate (1 chunk/slot) are constant across CUs.
  const int s  = (g < 8) ? g : 23 - g;
  const int jmax = 2 * s + 1;

  const int base  = bh * Sdim * Ddim;
  const int qbase = s * 128;

  // Fill region: block s owns chunks [s^2, (s+1)^2) of its bh's 256-chunk
  // region — allocation proportional to iteration count (2s+1 chunks over
  // 2s+2 iterations -> exactly one chunk per iteration except the last).
  f32x4* const fillp = (f32x4*)(out + OUT0)
                     + (size_t)bh * (CHUNKS_PER_BH * CHUNK_F4)
                     + (size_t)(s * s) * CHUNK_F4 + tid;
  const f32x4 z4 = (f32x4){0.f, 0.f, 0.f, 0.f};
  auto fill_chunk = [&](int c) {
    f32x4* zp = fillp + (size_t)c * CHUNK_F4;
    #pragma unroll
    for (int k = 0; k < 16; ++k)
      __builtin_nontemporal_store(z4, zp + k * 256);
  };

  // ---- Q fragments (B-operand), scale 1/8 folded. frag f: rows qbase+64f+16w.
  bf16x8 aq[2][2];
  #pragma unroll
  for (int f = 0; f < 2; ++f) {
    const float* qp = Q + base + (qbase + 64 * f + wave * 16 + l15) * Ddim + quad * 8;
    #pragma unroll
    for (int s2 = 0; s2 < 2; ++s2) {
      float4 a = *(const float4*)(qp + 32 * s2);
      float4 b = *(const float4*)(qp + 32 * s2 + 4);
      union { unsigned short u[8]; bf16x8 v; } u;
      u.u[0] = f2bf(a.x * 0.125f); u.u[1] = f2bf(a.y * 0.125f);
      u.u[2] = f2bf(a.z * 0.125f); u.u[3] = f2bf(a.w * 0.125f);
      u.u[4] = f2bf(b.x * 0.125f); u.u[5] = f2bf(b.y * 0.125f);
      u.u[6] = f2bf(b.z * 0.125f); u.u[7] = f2bf(b.w * 0.125f);
      aq[f][s2] = u.v;
    }
  }

  f32x4 ot[2][4];
  #pragma unroll
  for (int f = 0; f < 2; ++f)
    #pragma unroll
    for (int t = 0; t < 4; ++t) ot[f][t] = (f32x4){0.f, 0.f, 0.f, 0.f};
  float mrun[2] = {-__builtin_inff(), -__builtin_inff()};
  float lrun[2] = {0.f, 0.f};

  const float4* kg4 = (const float4*)(K + base);
  const float4* vg4 = (const float4*)(V + base);
  float4 kf[4], vf[4];

  auto ldtile = [&](int j) {
    const float4* kp = kg4 + j * 1024;
    const float4* vp = vg4 + j * 1024;
    #pragma unroll
    for (int i = 0; i < 4; ++i) { kf[i] = kp[i * 256 + tid]; vf[i] = vp[i * 256 + tid]; }
  };
  auto stage = [&](int buf) {
    #pragma unroll
    for (int i = 0; i < 4; ++i) {
      int lin = i * 256 + tid;
      int row = lin >> 4;
      int c4  = (lin & 15) << 2;
      uint2 t2;
      t2.x = (unsigned int)f2bf(kf[i].x) | ((unsigned int)f2bf(kf[i].y) << 16);
      t2.y = (unsigned int)f2bf(kf[i].z) | ((unsigned int)f2bf(kf[i].w) << 16);
      *(uint2*)&Klds[buf][row * LDK + c4] = t2;
      const int sw = vswz_m(c4) << 3;
      Vlds[buf][(c4 + 0) * LDK + (row ^ sw)] = f2bf(vf[i].x);
      Vlds[buf][(c4 + 1) * LDK + (row ^ sw)] = f2bf(vf[i].y);
      Vlds[buf][(c4 + 2) * LDK + (row ^ sw)] = f2bf(vf[i].z);
      Vlds[buf][(c4 + 3) * LDK + (row ^ sw)] = f2bf(vf[i].w);
    }
  };

  // ---- prologue
  ldtile(0); stage(0); ldtile(1);   // jmax >= 1 always

  for (int j = 0; j <= jmax; ++j) {
    block_sync_lds();
    if (j < jmax) stage((j + 1) & 1);
    if (j + 2 <= jmax) ldtile(j + 2);
    // Rate-matched zero-fill: one 64KiB chunk on every iteration except the
    // last (2s+1 chunks total). Chip-wide demand ~3.4 TB/s, uniform in time.
    if (j <= 2 * s) fill_chunk(j);

    const unsigned short* Kb = Klds[j & 1];
    const unsigned short* Vb = Vlds[j & 1];
    const bool f0act = (j <= 2 * s);   // frag0 has no columns at j == jmax

    // ---- S^T for both frags; K fragment read once, used twice
    f32x4 sc[2][4];
    #pragma unroll
    for (int f = 0; f < 2; ++f)
      #pragma unroll
      for (int t = 0; t < 4; ++t) sc[f][t] = (f32x4){0.f, 0.f, 0.f, 0.f};
    #pragma unroll
    for (int s2 = 0; s2 < 2; ++s2) {
      #pragma unroll
      for (int t = 0; t < 4; ++t) {
        bf16x8 ka = *(const bf16x8*)&Kb[(16 * t + l15) * LDK + 32 * s2 + quad * 8];
        sc[0][t] = __builtin_amdgcn_mfma_f32_16x16x32_bf16(ka, aq[0][s2], sc[0][t], 0, 0, 0);
        sc[1][t] = __builtin_amdgcn_mfma_f32_16x16x32_bf16(ka, aq[1][s2], sc[1][t], 0, 0, 0);
      }
    }

    // ---- causal diagonal masks (frag f diag at j == 2s+f; local coords equal)
    #pragma unroll
    for (int f = 0; f < 2; ++f) {
      if (j == 2 * s + f) {
        const int qml = wave * 16 + l15;
        #pragma unroll
        for (int t = 0; t < 4; ++t)
          #pragma unroll
          for (int r = 0; r < 4; ++r)
            if (16 * t + 4 * quad + r > qml) sc[f][t][r] = -__builtin_inff();
      }
    }

    // ---- online softmax + P write (per frag; frag0 skipped on final odd iter)
    #pragma unroll
    for (int f = 0; f < 2; ++f) {
      if (f == 0 && !f0act) continue;
      float mx = sc[f][0][0];
      #pragma unroll
      for (int t = 0; t < 4; ++t)
        #pragma unroll
        for (int r = 0; r < 4; ++r) mx = fmaxf(mx, sc[f][t][r]);
      mx = fmaxf(mx, __shfl_xor(mx, 16));
      mx = fmaxf(mx, __shfl_xor(mx, 32));
      float mn    = fmaxf(mrun[f], mx);
      float alpha = __builtin_amdgcn_exp2f((mrun[f] - mn) * LOG2E);
      float msc   = mn * LOG2E;
      mrun[f] = mn;
      float rs = 0.f;
      #pragma unroll
      for (int t = 0; t < 4; ++t)
        #pragma unroll
        for (int r = 0; r < 4; ++r) {
          float p = __builtin_amdgcn_exp2f(fmaf(sc[f][t][r], LOG2E, -msc));
          sc[f][t][r] = p;
          rs += p;
        }
      rs += __shfl_xor(rs, 16);
      rs += __shfl_xor(rs, 32);
      lrun[f] = lrun[f] * alpha + rs;
      #pragma unroll
      for (int t = 0; t < 4; ++t)
        #pragma unroll
        for (int r = 0; r < 4; ++r) ot[f][t][r] *= alpha;
      #pragma unroll
      for (int t = 0; t < 4; ++t) {
        uint2 pw;
        pw.x = (unsigned int)f2bf(sc[f][t][0]) | ((unsigned int)f2bf(sc[f][t][1]) << 16);
        pw.y = (unsigned int)f2bf(sc[f][t][2]) | ((unsigned int)f2bf(sc[f][t][3]) << 16);
        *(uint2*)&Plds[wave][f][l15 * LDK + 16 * t + 4 * quad] = pw;
      }
    }

    // ---- O^T += V^T * P^T; V fragment read once, used for both frags
    #pragma unroll
    for (int s2 = 0; s2 < 2; ++s2) {
      bf16x8 pb0, pb1;
      if (f0act) pb0 = *(const bf16x8*)&Plds[wave][0][l15 * LDK + 32 * s2 + quad * 8];
      pb1 = *(const bf16x8*)&Plds[wave][1][l15 * LDK + 32 * s2 + quad * 8];
      #pragma unroll
      for (int t = 0; t < 4; ++t) {
        const int d = 16 * t + l15;
        bf16x8 va = *(const bf16x8*)&Vb[d * LDK + (((4 * s2 + quad) ^ vswz_m(d)) << 3)];
        if (f0act)
          ot[0][t] = __builtin_amdgcn_mfma_f32_16x16x32_bf16(va, pb0, ot[0][t], 0, 0, 0);
        ot[1][t] = __builtin_amdgcn_mfma_f32_16x16x32_bf16(va, pb1, ot[1][t], 0, 0, 0);
      }
    }
  }

  // ---- epilogue
  #pragma unroll
  for (int f = 0; f < 2; ++f) {
    float inv = 1.0f / lrun[f];
    float* orow = out + base + (qbase + 64 * f + wave * 16 + l15) * Ddim + 4 * quad;
    #pragma unroll
    for (int t = 0; t < 4; ++t) {
      f32x4 o4;
      o4.x = ot[f][t][0] * inv; o4.y = ot[f][t][1] * inv;
      o4.z = ot[f][t][2] * inv; o4.w = ot[f][t][3] * inv;
      *(f32x4*)(orow + 16 * t) = o4;
    }
  }
}

extern "C" void kernel_launch(void* const* d_in, const int* in_sizes, int n_in,
                              void* d_out, int out_size, void* d_ws, size_t ws_size,
                              hipStream_t stream) {
  const float* q = (const float*)d_in[0];
  const float* k = (const float*)d_in[1];
  const float* v = (const float*)d_in[2];
  float* out = (float*)d_out;
  dim3 grid(BHn * STiles);   // 512 blocks: 32 bh x 16 supertiles, all co-resident
  flash_causal_kernel<<<grid, dim3(256), 0, stream>>>(q, k, v, out);
}

// Round 5
// 586.600 us; speedup vs baseline: 1.0335x; 1.0335x over previous
//
#include <hip/hip_runtime.h>

// TurboFlashAttention: causal B=2,H=16,S=2048,D=64 fp32 + 512MB zero placeholder.
// R10: revert to the proven R5 configuration (best measured: 589us) and remove
// its per-slot latency tax. Evidence across R5-R9: (1) in-loop fill scheduling
// is irrelevant (R7=R8=R9); (2) R5's interleave s-map beats the "complementary"
// map by ~16us -> co-location is contiguous-chunk (XCD x holds g={2x,2x+1};
// R5 pairs s=(x,15-x) -> every XCD exactly 34 slots); (3) tail fill (R5) is
// the best fill placement measured. New on top of R5: (a) raw lgkmcnt-only
// barrier instead of __syncthreads -- __syncthreads emits s_waitcnt vmcnt(0)
// which forces the just-issued j+2 prefetch loads (~900cyc) onto the critical
// path EVERY slot; the raw barrier lets them ride their 2-slot slack
// (correctness validated in R8/R9: passed, absmax unchanged). (b) s_setprio(1)
// around MFMA clusters: 2 independent blocks/CU at different phases is the
// regime where setprio measured +4-7% (attn, m191).

typedef __bf16 bf16x8 __attribute__((ext_vector_type(8)));
typedef float f32x4 __attribute__((ext_vector_type(4)));

#define LOG2E 1.44269504088896340736f

__device__ __forceinline__ unsigned short f2bf(float f) {
  unsigned int u = __float_as_uint(f);
  u += 0x7fffu + ((u >> 16) & 1u);   // RNE
  return (unsigned short)(u >> 16);
}

// Cross-wave LDS sync WITHOUT the vmcnt(0) drain __syncthreads would emit.
// LDS producer->consumer and WAR hazards need only each wave's own ds ops
// drained (lgkmcnt(0)); global loads are consumed via compiler-counted vmcnt.
__device__ __forceinline__ void block_sync_lds() {
  asm volatile("s_waitcnt lgkmcnt(0)" ::: "memory");
  __builtin_amdgcn_s_barrier();
}

constexpr int Sdim = 2048, Ddim = 64, BHn = 32;
constexpr int STiles = 16;                   // 128-row q-supertiles
constexpr int LDK = 72;                      // LDS leading-dim pad (shorts)
constexpr int OUT0 = BHn * Sdim * Ddim;      // output-region floats
constexpr size_t FILL_PER_BH = 1048576;      // f32x4 per bh in placeholder

__device__ __forceinline__ int vswz_m(int d) { return ((d >> 2) ^ (d >> 5)) & 7; }

__global__ __launch_bounds__(256, 2)
void flash_causal_kernel(const float* __restrict__ Q, const float* __restrict__ K,
                         const float* __restrict__ V, float* __restrict__ out) {
  __shared__ unsigned short Klds[2][64 * LDK];      // K tile [kn][d]
  __shared__ unsigned short Vlds[2][64 * LDK];      // V^T tile [d][kn^swz]
  __shared__ unsigned short Plds[4][2][16 * LDK];   // per-wave, per-frag P^T

  const int tid  = threadIdx.x;
  const int wave = tid >> 6;
  const int lane = tid & 63;
  const int quad = lane >> 4;
  const int l15  = lane & 15;

  const int bh = blockIdx.x & (BHn - 1);
  const int g  = (int)(blockIdx.x >> 5);                        // 0..15
  const int s  = (g & 1) ? (STiles - 1) - (g >> 1) : (g >> 1);  // interleave
  const int jmax = 2 * s + 1;

  const int base  = bh * Sdim * Ddim;
  const int qbase = s * 128;

  // ---- Q fragments (B-operand), scale 1/8 folded. frag f: rows qbase+64f+16w.
  bf16x8 aq[2][2];
  #pragma unroll
  for (int f = 0; f < 2; ++f) {
    const float* qp = Q + base + (qbase + 64 * f + wave * 16 + l15) * Ddim + quad * 8;
    #pragma unroll
    for (int s2 = 0; s2 < 2; ++s2) {
      float4 a = *(const float4*)(qp + 32 * s2);
      float4 b = *(const float4*)(qp + 32 * s2 + 4);
      union { unsigned short u[8]; bf16x8 v; } u;
      u.u[0] = f2bf(a.x * 0.125f); u.u[1] = f2bf(a.y * 0.125f);
      u.u[2] = f2bf(a.z * 0.125f); u.u[3] = f2bf(a.w * 0.125f);
      u.u[4] = f2bf(b.x * 0.125f); u.u[5] = f2bf(b.y * 0.125f);
      u.u[6] = f2bf(b.z * 0.125f); u.u[7] = f2bf(b.w * 0.125f);
      aq[f][s2] = u.v;
    }
  }

  f32x4 ot[2][4];
  #pragma unroll
  for (int f = 0; f < 2; ++f)
    #pragma unroll
    for (int t = 0; t < 4; ++t) ot[f][t] = (f32x4){0.f, 0.f, 0.f, 0.f};
  float mrun[2] = {-__builtin_inff(), -__builtin_inff()};
  float lrun[2] = {0.f, 0.f};

  const float4* kg4 = (const float4*)(K + base);
  const float4* vg4 = (const float4*)(V + base);
  float4 kf[4], vf[4];

  auto ldtile = [&](int j) {
    const float4* kp = kg4 + j * 1024;
    const float4* vp = vg4 + j * 1024;
    #pragma unroll
    for (int i = 0; i < 4; ++i) { kf[i] = kp[i * 256 + tid]; vf[i] = vp[i * 256 + tid]; }
  };
  auto stage = [&](int buf) {
    #pragma unroll
    for (int i = 0; i < 4; ++i) {
      int lin = i * 256 + tid;
      int row = lin >> 4;
      int c4  = (lin & 15) << 2;
      uint2 t2;
      t2.x = (unsigned int)f2bf(kf[i].x) | ((unsigned int)f2bf(kf[i].y) << 16);
      t2.y = (unsigned int)f2bf(kf[i].z) | ((unsigned int)f2bf(kf[i].w) << 16);
      *(uint2*)&Klds[buf][row * LDK + c4] = t2;
      const int sw = vswz_m(c4) << 3;
      Vlds[buf][(c4 + 0) * LDK + (row ^ sw)] = f2bf(vf[i].x);
      Vlds[buf][(c4 + 1) * LDK + (row ^ sw)] = f2bf(vf[i].y);
      Vlds[buf][(c4 + 2) * LDK + (row ^ sw)] = f2bf(vf[i].z);
      Vlds[buf][(c4 + 3) * LDK + (row ^ sw)] = f2bf(vf[i].w);
    }
  };

  // ---- prologue
  ldtile(0); stage(0); ldtile(1);   // jmax >= 1 always

  for (int j = 0; j <= jmax; ++j) {
    block_sync_lds();
    if (j < jmax) stage((j + 1) & 1);
    if (j + 2 <= jmax) ldtile(j + 2);

    const unsigned short* Kb = Klds[j & 1];
    const unsigned short* Vb = Vlds[j & 1];
    const bool f0act = (j <= 2 * s);   // frag0 has no columns at j == jmax

    // ---- S^T for both frags; K fragment read once, used twice
    f32x4 sc[2][4];
    #pragma unroll
    for (int f = 0; f < 2; ++f)
      #pragma unroll
      for (int t = 0; t < 4; ++t) sc[f][t] = (f32x4){0.f, 0.f, 0.f, 0.f};
    __builtin_amdgcn_s_setprio(1);
    #pragma unroll
    for (int s2 = 0; s2 < 2; ++s2) {
      #pragma unroll
      for (int t = 0; t < 4; ++t) {
        bf16x8 ka = *(const bf16x8*)&Kb[(16 * t + l15) * LDK + 32 * s2 + quad * 8];
        sc[0][t] = __builtin_amdgcn_mfma_f32_16x16x32_bf16(ka, aq[0][s2], sc[0][t], 0, 0, 0);
        sc[1][t] = __builtin_amdgcn_mfma_f32_16x16x32_bf16(ka, aq[1][s2], sc[1][t], 0, 0, 0);
      }
    }
    __builtin_amdgcn_s_setprio(0);

    // ---- causal diagonal masks (frag f diag at j == 2s+f; local coords equal)
    #pragma unroll
    for (int f = 0; f < 2; ++f) {
      if (j == 2 * s + f) {
        const int qml = wave * 16 + l15;
        #pragma unroll
        for (int t = 0; t < 4; ++t)
          #pragma unroll
          for (int r = 0; r < 4; ++r)
            if (16 * t + 4 * quad + r > qml) sc[f][t][r] = -__builtin_inff();
      }
    }

    // ---- online softmax + P write (per frag; frag0 skipped on final odd iter)
    #pragma unroll
    for (int f = 0; f < 2; ++f) {
      if (f == 0 && !f0act) continue;
      float mx = sc[f][0][0];
      #pragma unroll
      for (int t = 0; t < 4; ++t)
        #pragma unroll
        for (int r = 0; r < 4; ++r) mx = fmaxf(mx, sc[f][t][r]);
      mx = fmaxf(mx, __shfl_xor(mx, 16));
      mx = fmaxf(mx, __shfl_xor(mx, 32));
      float mn    = fmaxf(mrun[f], mx);
      float alpha = __builtin_amdgcn_exp2f((mrun[f] - mn) * LOG2E);
      float msc   = mn * LOG2E;
      mrun[f] = mn;
      float rs = 0.f;
      #pragma unroll
      for (int t = 0; t < 4; ++t)
        #pragma unroll
        for (int r = 0; r < 4; ++r) {
          float p = __builtin_amdgcn_exp2f(fmaf(sc[f][t][r], LOG2E, -msc));
          sc[f][t][r] = p;
          rs += p;
        }
      rs += __shfl_xor(rs, 16);
      rs += __shfl_xor(rs, 32);
      lrun[f] = lrun[f] * alpha + rs;
      #pragma unroll
      for (int t = 0; t < 4; ++t)
        #pragma unroll
        for (int r = 0; r < 4; ++r) ot[f][t][r] *= alpha;
      #pragma unroll
      for (int t = 0; t < 4; ++t) {
        uint2 pw;
        pw.x = (unsigned int)f2bf(sc[f][t][0]) | ((unsigned int)f2bf(sc[f][t][1]) << 16);
        pw.y = (unsigned int)f2bf(sc[f][t][2]) | ((unsigned int)f2bf(sc[f][t][3]) << 16);
        *(uint2*)&Plds[wave][f][l15 * LDK + 16 * t + 4 * quad] = pw;
      }
    }

    // ---- O^T += V^T * P^T; V fragment read once, used for both frags
    __builtin_amdgcn_s_setprio(1);
    #pragma unroll
    for (int s2 = 0; s2 < 2; ++s2) {
      bf16x8 pb0, pb1;
      if (f0act) pb0 = *(const bf16x8*)&Plds[wave][0][l15 * LDK + 32 * s2 + quad * 8];
      pb1 = *(const bf16x8*)&Plds[wave][1][l15 * LDK + 32 * s2 + quad * 8];
      #pragma unroll
      for (int t = 0; t < 4; ++t) {
        const int d = 16 * t + l15;
        bf16x8 va = *(const bf16x8*)&Vb[d * LDK + (((4 * s2 + quad) ^ vswz_m(d)) << 3)];
        if (f0act)
          ot[0][t] = __builtin_amdgcn_mfma_f32_16x16x32_bf16(va, pb0, ot[0][t], 0, 0, 0);
        ot[1][t] = __builtin_amdgcn_mfma_f32_16x16x32_bf16(va, pb1, ot[1][t], 0, 0, 0);
      }
    }
    __builtin_amdgcn_s_setprio(0);
  }

  // ---- epilogue
  #pragma unroll
  for (int f = 0; f < 2; ++f) {
    float inv = 1.0f / lrun[f];
    float* orow = out + base + (qbase + 64 * f + wave * 16 + l15) * Ddim + 4 * quad;
    #pragma unroll
    for (int t = 0; t < 4; ++t) {
      f32x4 o4;
      o4.x = ot[f][t][0] * inv; o4.y = ot[f][t][1] * inv;
      o4.z = ot[f][t][2] * inv; o4.w = ot[f][t][3] * inv;
      *(f32x4*)(orow + 16 * t) = o4;
    }
  }

  // ---- zero-fill placeholder, share inverse to compute (fill-rank gp).
  {
    const int gp = (STiles - 1) - s;             // 0 = heaviest compute
    const int w  = 2 * gp + 1;
    const size_t start_f4 = (size_t)bh * FILL_PER_BH + (size_t)4096 * (gp * gp);
    const size_t count_f4 = (size_t)4096 * w;
    f32x4 z4 = (f32x4){0.f, 0.f, 0.f, 0.f};
    f32x4* zp = (f32x4*)(out + OUT0) + start_f4;
    for (size_t i = tid; i < count_f4; i += 256)
      __builtin_nontemporal_store(z4, zp + i);
  }
}

extern "C" void kernel_launch(void* const* d_in, const int* in_sizes, int n_in,
                              void* d_out, int out_size, void* d_ws, size_t ws_size,
                              hipStream_t stream) {
  const float* q = (const float*)d_in[0];
  const float* k = (const float*)d_in[1];
  const float* v = (const float*)d_in[2];
  float* out = (float*)d_out;
  dim3 grid(BHn * STiles);   // 512 blocks: 32 bh x 16 supertiles, all co-resident
  flash_causal_kernel<<<grid, dim3(256), 0, stream>>>(q, k, v, out);
}